// Round 1
// baseline (318.072 us; speedup 1.0000x reference)
//
#include <hip/hip_runtime.h>

#define NN   4096
#define NE   5
#define NC   2
#define FINF 128
#define FOUTF 64
#define CAP  384
#define YP   132   // row pitch for Y panels (129 used: 128 features + 1 ones-col)

// ---------------- workspace layout (bytes) ----------------
// cnt      : NN * 4                  @ 0
// col_u    : NN*CAP*4 = 6291456      @ 16384
// col_vals : NN*CAP*5*4 = 31457280   @ 6307840
// Y_A      : NC*NN*YP*4 = 4325376    @ 37765120
// Y_1      : 4325376                 @ 42090496
// Y_2      : 4325376                 @ 46415872
// total ~ 50.8 MB

__global__ void build_csc(const float* __restrict__ A,
                          int* __restrict__ cnt,
                          int* __restrict__ col_u,
                          float* __restrict__ col_vals)
{
    const size_t S = (size_t)NN * NN / 4;   // float4 count per e-slice
    const float4* A4 = (const float4*)A;
    size_t stride = (size_t)gridDim.x * blockDim.x;
    for (size_t i = (size_t)blockIdx.x * blockDim.x + threadIdx.x; i < S; i += stride) {
        float4 q0 = A4[i];
        float4 q1 = A4[i + S];
        float4 q2 = A4[i + 2 * S];
        float4 q3 = A4[i + 3 * S];
        float4 q4 = A4[i + 4 * S];
        int u  = (int)(i >> 10);           // 1024 float4 per row
        int v0 = ((int)i & 1023) << 2;
#define DO_COMP(comp, joff)                                                     \
        {                                                                       \
            float b0 = q0.comp, b1 = q1.comp, b2 = q2.comp,                     \
                  b3 = q3.comp, b4 = q4.comp;                                   \
            if (b0 != 0.f || b1 != 0.f || b2 != 0.f || b3 != 0.f || b4 != 0.f) {\
                int v = v0 + joff;                                              \
                int pos = atomicAdd(&cnt[v], 1);                                \
                if (pos < CAP) {                                                \
                    int slot = v * CAP + pos;                                   \
                    col_u[slot] = u;                                            \
                    float* vp = col_vals + (size_t)slot * 5;                    \
                    vp[0] = b0; vp[1] = b1; vp[2] = b2; vp[3] = b3; vp[4] = b4; \
                }                                                               \
            }                                                                   \
        }
        DO_COMP(x, 0)
        DO_COMP(y, 1)
        DO_COMP(z, 2)
        DO_COMP(w, 3)
#undef DO_COMP
    }
}

// One workgroup per column v. Handles both channels.
// Y[c][v][f] = invS_c * sum_i w_c(i) * X_c[u_i][f],  f in [0,129)
// where w_c(i) = (do_exp ? exp(dot(filt[c], vals_i)) : dot(filt[c], vals_i))
// invS_c = 1/sum_i w_c(i) when do_exp (softmax right-norm), else 1.
// shared_x: X is h [NN,FINF] (same for both channels), f==128 -> 1.0 (ones col)
// else:     X is [NC,NN,YP] (previous Y panel)
__global__ __launch_bounds__(256) void spmm_col(
    const int* __restrict__ cnt,
    const int* __restrict__ col_u,
    const float* __restrict__ col_vals,
    const float* __restrict__ filt,   // [NC, NE]
    const float* __restrict__ X,
    float* __restrict__ Y,            // [NC, NN, YP]
    int shared_x, int do_exp)
{
    int v = blockIdx.x;
    int n = cnt[v];
    if (n > CAP) n = CAP;

    __shared__ float s_w0[CAP];
    __shared__ float s_w1[CAP];
    __shared__ int   s_u[CAP];
    __shared__ float s_sum[2];

    int tid = threadIdx.x;
    if (tid < 2) s_sum[tid] = 0.f;
    __syncthreads();

    float f00 = filt[0], f01 = filt[1], f02 = filt[2], f03 = filt[3], f04 = filt[4];
    float f10 = filt[5], f11 = filt[6], f12 = filt[7], f13 = filt[8], f14 = filt[9];

    float lsum0 = 0.f, lsum1 = 0.f;
    for (int i = tid; i < n; i += 256) {
        const float* vp = col_vals + ((size_t)v * CAP + i) * 5;
        float a0 = vp[0], a1 = vp[1], a2 = vp[2], a3 = vp[3], a4 = vp[4];
        s_u[i] = col_u[v * CAP + i];
        float s0 = f00 * a0 + f01 * a1 + f02 * a2 + f03 * a3 + f04 * a4;
        float s1 = f10 * a0 + f11 * a1 + f12 * a2 + f13 * a3 + f14 * a4;
        if (do_exp) { s0 = __expf(s0); s1 = __expf(s1); }
        s_w0[i] = s0;
        s_w1[i] = s1;
        lsum0 += s0;
        lsum1 += s1;
    }
    if (do_exp) {
        atomicAdd(&s_sum[0], lsum0);
        atomicAdd(&s_sum[1], lsum1);
    }
    __syncthreads();

    float inv0 = 1.f, inv1 = 1.f;
    if (do_exp && n > 0) {
        inv0 = 1.f / s_sum[0];
        inv1 = 1.f / s_sum[1];
    }

    if (tid < 129) {
        int f = tid;
        float acc0 = 0.f, acc1 = 0.f;
        if (shared_x) {
            for (int i = 0; i < n; ++i) {
                int u = s_u[i];
                float xv = (f < FINF) ? X[(size_t)u * FINF + f] : 1.0f;
                acc0 += s_w0[i] * xv;
                acc1 += s_w1[i] * xv;
            }
        } else {
            const float* X0 = X;
            const float* X1 = X + (size_t)NN * YP;
            for (int i = 0; i < n; ++i) {
                int u = s_u[i];
                acc0 += s_w0[i] * X0[(size_t)u * YP + f];
                acc1 += s_w1[i] * X1[(size_t)u * YP + f];
            }
        }
        Y[((size_t)0 * NN + v) * YP + f] = acc0 * inv0;
        Y[((size_t)1 * NN + v) * YP + f] = acc1 * inv1;
    }
}

// out[c,l,v,o] = relu( sum_f (Y_l[c][v][f] / d) * gW[c,f,o] + gb[c,o] )
// d = Y_l[c][v][128] if != 0 else 1
__global__ __launch_bounds__(64) void gcn_out(
    const float* __restrict__ YA,
    const float* __restrict__ Y1,
    const float* __restrict__ Y2,
    const float* __restrict__ gW,   // [NC, FINF, FOUTF]
    const float* __restrict__ gb,   // [NC, FOUTF]
    float* __restrict__ out)        // [NC, 3, NN, FOUTF]
{
    int b = blockIdx.x;
    int v  = b & (NN - 1);
    int cl = b >> 12;              // 0..5, cl = c*3 + l
    int c = cl / 3, l = cl % 3;
    const float* Y = (l == 0) ? YA : (l == 1) ? Y1 : Y2;
    const float* yrow = Y + ((size_t)c * NN + v) * YP;

    __shared__ float s_y[FINF];
    __shared__ float s_inv;
    int t = threadIdx.x;
    s_y[t]      = yrow[t];
    s_y[t + 64] = yrow[t + 64];
    if (t == 0) {
        float d = yrow[128];
        s_inv = (d != 0.f) ? (1.f / d) : 1.f;
    }
    __syncthreads();

    float inv = s_inv;
    float acc = gb[c * FOUTF + t];
    const float* w = gW + (size_t)c * FINF * FOUTF + t;
#pragma unroll 8
    for (int f = 0; f < FINF; ++f)
        acc += (s_y[f] * inv) * w[(size_t)f * FOUTF];
    out[((size_t)cl * NN + v) * FOUTF + t] = fmaxf(acc, 0.f);
}

extern "C" void kernel_launch(void* const* d_in, const int* in_sizes, int n_in,
                              void* d_out, int out_size, void* d_ws, size_t ws_size,
                              hipStream_t stream)
{
    const float* A     = (const float*)d_in[0];
    const float* h     = (const float*)d_in[1];
    const float* W1_0  = (const float*)d_in[2];
    const float* W2_0  = (const float*)d_in[3];
    const float* W1_1  = (const float*)d_in[4];
    const float* gW    = (const float*)d_in[5];
    const float* gb    = (const float*)d_in[6];
    float* out = (float*)d_out;

    char* ws = (char*)d_ws;
    int*   cnt      = (int*)(ws);
    int*   col_u    = (int*)(ws + 16384);
    float* col_vals = (float*)(ws + 6307840);
    float* YA       = (float*)(ws + 37765120);
    float* Y1       = (float*)(ws + 42090496);
    float* Y2       = (float*)(ws + 46415872);

    hipMemsetAsync(cnt, 0, NN * sizeof(int), stream);
    build_csc<<<2048, 256, 0, stream>>>(A, cnt, col_u, col_vals);

    // Stage A: Y_A = RA^T [h|1]   (softmax-normalized weights from W1_0)
    spmm_col<<<NN, 256, 0, stream>>>(cnt, col_u, col_vals, W1_0, h,  YA, 1, 1);
    // Stage B: Y_1 = RB^T Y_A = (RA RB)^T [h|1] = H0^T [h|1]
    spmm_col<<<NN, 256, 0, stream>>>(cnt, col_u, col_vals, W2_0, YA, Y1, 0, 1);
    // Stage C: Y_2 = RB1^T Y_1 = H1^T [h|1]   (plain gtconv weights, no softmax)
    spmm_col<<<NN, 256, 0, stream>>>(cnt, col_u, col_vals, W1_1, Y1, Y2, 0, 0);

    gcn_out<<<6 * NN, 64, 0, stream>>>(YA, Y1, Y2, gW, gb, out);
}

// Round 2
// 273.018 us; speedup vs baseline: 1.1650x; 1.1650x over previous
//
#include <hip/hip_runtime.h>

#define NN    4096
#define NE    5
#define NC    2
#define FINF  128
#define FOUTF 64
#define CAP   384
#define YP    132   // row pitch for Y panels (129 used: 128 features + 1 denom col)
#define VB    16    // columns per gcn_out block

// ---------------- workspace layout (bytes) ----------------
// cnt    : NN*4 = 16384            @ 0
// edges  : NN*CAP*32 = 50331648    @ 16384       (2 x float4 per edge slot)
//          edge slot: {u(bits), wA0, wA1, wB0}, {wB1, wC0, wC1, pad}
// Y_A    : NC*NN*YP*4 = 4325376    @ 50348032
// Y_1    : 4325376                 @ 54673408
// Y_2    : 4325376                 @ 58998784
// total ~ 63.3 MB

__global__ __launch_bounds__(256) void zero_cnt(int4* __restrict__ cnt4)
{
    cnt4[blockIdx.x * 256 + threadIdx.x] = int4{0, 0, 0, 0};   // grid 4 -> 1024 int4 = 4096 ints
}

__global__ __launch_bounds__(256) void build_csc(
    const float* __restrict__ A,
    const float* __restrict__ W1_0,
    const float* __restrict__ W2_0,
    const float* __restrict__ W1_1,
    int*    __restrict__ cnt,
    float4* __restrict__ edges)
{
    // filters: [C,E]; broadcast scalar loads (L1-resident)
    float fA0[NE], fA1[NE], fB0[NE], fB1[NE], fC0[NE], fC1[NE];
#pragma unroll
    for (int e = 0; e < NE; ++e) {
        fA0[e] = W1_0[e];      fA1[e] = W1_0[NE + e];
        fB0[e] = W2_0[e];      fB1[e] = W2_0[NE + e];
        fC0[e] = W1_1[e];      fC1[e] = W1_1[NE + e];
    }

    const size_t S = (size_t)NN * NN / 4;   // float4 per e-slice
    const float4* A4 = (const float4*)A;
    size_t stride = (size_t)gridDim.x * blockDim.x;
    for (size_t i = (size_t)blockIdx.x * blockDim.x + threadIdx.x; i < S; i += stride) {
        float4 q0 = A4[i];
        float4 q1 = A4[i + S];
        float4 q2 = A4[i + 2 * S];
        float4 q3 = A4[i + 3 * S];
        float4 q4 = A4[i + 4 * S];
        int u  = (int)(i >> 10);            // 1024 float4 per row
        int v0 = ((int)i & 1023) << 2;
#define DO_COMP(comp, joff)                                                      \
        {                                                                        \
            float a0 = q0.comp, a1 = q1.comp, a2 = q2.comp,                      \
                  a3 = q3.comp, a4 = q4.comp;                                    \
            if (a0 != 0.f || a1 != 0.f || a2 != 0.f || a3 != 0.f || a4 != 0.f) { \
                float sA0 = fA0[0]*a0 + fA0[1]*a1 + fA0[2]*a2 + fA0[3]*a3 + fA0[4]*a4; \
                float sA1 = fA1[0]*a0 + fA1[1]*a1 + fA1[2]*a2 + fA1[3]*a3 + fA1[4]*a4; \
                float sB0 = fB0[0]*a0 + fB0[1]*a1 + fB0[2]*a2 + fB0[3]*a3 + fB0[4]*a4; \
                float sB1 = fB1[0]*a0 + fB1[1]*a1 + fB1[2]*a2 + fB1[3]*a3 + fB1[4]*a4; \
                float sC0 = fC0[0]*a0 + fC0[1]*a1 + fC0[2]*a2 + fC0[3]*a3 + fC0[4]*a4; \
                float sC1 = fC1[0]*a0 + fC1[1]*a1 + fC1[2]*a2 + fC1[3]*a3 + fC1[4]*a4; \
                int v = v0 + joff;                                               \
                int pos = atomicAdd(&cnt[v], 1);                                 \
                if (pos < CAP) {                                                 \
                    size_t slot = ((size_t)v * CAP + pos) * 2;                   \
                    edges[slot]     = float4{__int_as_float(u), __expf(sA0),     \
                                             __expf(sA1), __expf(sB0)};          \
                    edges[slot + 1] = float4{__expf(sB1), sC0, sC1, 0.f};        \
                }                                                                \
            }                                                                    \
        }
        DO_COMP(x, 0)
        DO_COMP(y, 1)
        DO_COMP(z, 2)
        DO_COMP(w, 3)
#undef DO_COMP
    }
}

// One workgroup (256 threads) per column v; both channels.
// STAGE 0: X = h [NN,FINF] shared by channels, softmax-normalize, denom col = sum(w)
// STAGE 1: X = prev Y panel [NC,NN,YP], softmax-normalize, denom col gathered
// STAGE 2: X = prev Y panel, no normalization, denom col gathered
template<int STAGE>
__global__ __launch_bounds__(256) void spmm_col(
    const int*    __restrict__ cnt,
    const float4* __restrict__ edges,
    const float*  __restrict__ X,
    float*        __restrict__ Y)
{
    int v = blockIdx.x;
    int n = cnt[v];
    if (n > CAP) n = CAP;

    __shared__ float2 s_p0[CAP];   // {u bits, w0}
    __shared__ float2 s_p1[CAP];   // {u bits, w1}
    __shared__ float  s_red[4];    // sum0, sum1, d0, d1

    int tid = threadIdx.x;
    if (tid < 4) s_red[tid] = 0.f;
    __syncthreads();

    float l0 = 0.f, l1 = 0.f, ld0 = 0.f, ld1 = 0.f;
    for (int i = tid; i < n; i += 256) {
        size_t slot = ((size_t)v * CAP + i) * 2;
        float4 q0 = edges[slot];
        float4 q1 = edges[slot + 1];
        float w0, w1;
        if      (STAGE == 0) { w0 = q0.y; w1 = q0.z; }
        else if (STAGE == 1) { w0 = q0.w; w1 = q1.x; }
        else                 { w0 = q1.y; w1 = q1.z; }
        s_p0[i] = float2{q0.x, w0};
        s_p1[i] = float2{q0.x, w1};
        l0 += w0;
        l1 += w1;
        if (STAGE != 0) {
            int u = __float_as_int(q0.x);
            ld0 += w0 * X[(size_t)u * YP + FINF];
            ld1 += w1 * X[(size_t)(NN + u) * YP + FINF];
        }
    }
    if (STAGE == 0) { ld0 = l0; ld1 = l1; }

#pragma unroll
    for (int m = 32; m >= 1; m >>= 1) {
        l0  += __shfl_xor(l0,  m);
        l1  += __shfl_xor(l1,  m);
        ld0 += __shfl_xor(ld0, m);
        ld1 += __shfl_xor(ld1, m);
    }
    if ((tid & 63) == 0) {
        atomicAdd(&s_red[0], l0);
        atomicAdd(&s_red[1], l1);
        atomicAdd(&s_red[2], ld0);
        atomicAdd(&s_red[3], ld1);
    }
    __syncthreads();

    int c = tid >> 7, f = tid & 127;
    float inv = 1.f;
    if (STAGE < 2 && n > 0) inv = 1.f / s_red[c];
    float dv = s_red[2 + c];

    const float2* sp = c ? s_p1 : s_p0;
    float acc = 0.f;
    if (STAGE == 0) {
        const float* Xb = X + f;
#pragma unroll 4
        for (int i = 0; i < n; ++i) {
            float2 p = sp[i];
            acc += p.y * Xb[(size_t)__float_as_int(p.x) * FINF];
        }
    } else {
        const float* Xb = X + (size_t)c * NN * YP + f;
#pragma unroll 4
        for (int i = 0; i < n; ++i) {
            float2 p = sp[i];
            acc += p.y * Xb[(size_t)__float_as_int(p.x) * YP];
        }
    }
    float* yrow = Y + ((size_t)c * NN + v) * YP;
    yrow[f] = acc * inv;
    if (f == 0) yrow[FINF] = dv * inv;
}

// out[c,l,v,o] = relu( (sum_f Y_l[c][v][f] gW[c,f,o]) * inv_d + gb[c,o] )
__global__ __launch_bounds__(64) void gcn_out(
    const float* __restrict__ YA,
    const float* __restrict__ Y1,
    const float* __restrict__ Y2,
    const float* __restrict__ gW,   // [NC, FINF, FOUTF]
    const float* __restrict__ gb,   // [NC, FOUTF]
    float* __restrict__ out)        // [NC, 3, NN, FOUTF]
{
    const int grids_per_cl = NN / VB;
    int b   = blockIdx.x;
    int grp = b / grids_per_cl;           // cl = c*3 + l
    int v0  = (b % grids_per_cl) * VB;
    int c = grp / 3, l = grp % 3;
    const float* Y = (l == 0) ? YA : (l == 1) ? Y1 : Y2;

    __shared__ float s_y[VB][FINF];
    __shared__ float s_inv[VB];
    int t = threadIdx.x;

    for (int k = t; k < VB * (FINF / 4); k += 64) {
        int r = k >> 5, c4 = k & 31;
        float4 q = *(const float4*)(Y + ((size_t)c * NN + v0 + r) * YP + c4 * 4);
        *(float4*)&s_y[r][c4 * 4] = q;
    }
    if (t < VB) {
        float d = Y[((size_t)c * NN + v0 + t) * YP + FINF];
        s_inv[t] = (d != 0.f) ? (1.f / d) : 1.f;
    }
    __syncthreads();

    float acc[VB];
#pragma unroll
    for (int r = 0; r < VB; ++r) acc[r] = 0.f;

    const float* w = gW + (size_t)c * FINF * FOUTF + t;
    for (int f4 = 0; f4 < FINF / 4; ++f4) {
        float w0 = w[(size_t)(f4 * 4 + 0) * FOUTF];
        float w1 = w[(size_t)(f4 * 4 + 1) * FOUTF];
        float w2 = w[(size_t)(f4 * 4 + 2) * FOUTF];
        float w3 = w[(size_t)(f4 * 4 + 3) * FOUTF];
#pragma unroll
        for (int r = 0; r < VB; ++r) {
            float4 y4 = *(const float4*)&s_y[r][f4 * 4];
            acc[r] += y4.x * w0 + y4.y * w1 + y4.z * w2 + y4.w * w3;
        }
    }

    float bias = gb[c * FOUTF + t];
#pragma unroll
    for (int r = 0; r < VB; ++r) {
        float val = acc[r] * s_inv[r] + bias;
        out[((size_t)grp * NN + v0 + r) * FOUTF + t] = fmaxf(val, 0.f);
    }
}

extern "C" void kernel_launch(void* const* d_in, const int* in_sizes, int n_in,
                              void* d_out, int out_size, void* d_ws, size_t ws_size,
                              hipStream_t stream)
{
    const float* A     = (const float*)d_in[0];
    const float* h     = (const float*)d_in[1];
    const float* W1_0  = (const float*)d_in[2];
    const float* W2_0  = (const float*)d_in[3];
    const float* W1_1  = (const float*)d_in[4];
    const float* gW    = (const float*)d_in[5];
    const float* gb    = (const float*)d_in[6];
    float* out = (float*)d_out;

    char* ws = (char*)d_ws;
    int*    cnt   = (int*)(ws);
    float4* edges = (float4*)(ws + 16384);
    float*  YA    = (float*)(ws + 50348032);
    float*  Y1    = (float*)(ws + 54673408);
    float*  Y2    = (float*)(ws + 58998784);

    zero_cnt<<<4, 256, 0, stream>>>((int4*)cnt);
    build_csc<<<2048, 256, 0, stream>>>(A, W1_0, W2_0, W1_1, cnt, edges);

    // Stage A: Y_A = RA^T [h|1]           (softmax weights wA)
    spmm_col<0><<<NN, 256, 0, stream>>>(cnt, edges, h,  YA);
    // Stage B: Y_1 = RB^T Y_A = H0^T [h|1] (softmax weights wB)
    spmm_col<1><<<NN, 256, 0, stream>>>(cnt, edges, YA, Y1);
    // Stage C: Y_2 = RB1^T Y_1 = H1^T [h|1] (raw gtconv weights wC)
    spmm_col<2><<<NN, 256, 0, stream>>>(cnt, edges, Y1, Y2);

    gcn_out<<<6 * NN / VB, 64, 0, stream>>>(YA, Y1, Y2, gW, gb, out);
}

// Round 3
// 227.282 us; speedup vs baseline: 1.3995x; 1.2012x over previous
//
#include <hip/hip_runtime.h>
#include <hip/hip_bf16.h>

#define NN    4096
#define NE    5
#define NC    2
#define FINF  128
#define FOUTF 64
#define CAP   384
#define YP    132   // fp32 Y panel pitch (128 features + denom at [128])
#define VB    16    // columns per gcn_out block

// ---------------- workspace layout (bytes) ----------------
// cnt  @ 0          : 16384
// eu   @ 16384      : NN*CAP*4  = 6291456
// wA   @ 6307840    : NN*CAP*8  = 12582912
// wB   @ 18890752   : 12582912
// wC   @ 31473664   : 12582912
// YA   @ 44056576   : NC*NN*YP*4 = 4325376
// Y1   @ 48381952   : 4325376
// Y2   @ 52707328   : 4325376
// DdA  @ 57032704   : NC*NN*4 = 32768
// Dd1  @ 57065472   : 32768
// XbA  @ 57098240   : NC*NN*128*2 = 2097152   (bf16 gather panel)
// Xb1  @ 59195392   : 2097152
// end ~ 61.3 MB

__global__ __launch_bounds__(256) void zero_cnt(int4* __restrict__ cnt4)
{
    cnt4[blockIdx.x * 256 + threadIdx.x] = int4{0, 0, 0, 0};   // grid 4 -> 4096 ints
}

__global__ __launch_bounds__(256) void build_csc(
    const float* __restrict__ A,
    const float* __restrict__ W1_0,
    const float* __restrict__ W2_0,
    const float* __restrict__ W1_1,
    int*    __restrict__ cnt,
    int*    __restrict__ eu,
    float2* __restrict__ wA,
    float2* __restrict__ wB,
    float2* __restrict__ wC)
{
    float fA0[NE], fA1[NE], fB0[NE], fB1[NE], fC0[NE], fC1[NE];
#pragma unroll
    for (int e = 0; e < NE; ++e) {
        fA0[e] = W1_0[e];      fA1[e] = W1_0[NE + e];
        fB0[e] = W2_0[e];      fB1[e] = W2_0[NE + e];
        fC0[e] = W1_1[e];      fC1[e] = W1_1[NE + e];
    }

    const size_t S = (size_t)NN * NN / 4;   // float4 per e-slice
    const float4* A4 = (const float4*)A;
    size_t stride = (size_t)gridDim.x * blockDim.x;
    for (size_t i = (size_t)blockIdx.x * blockDim.x + threadIdx.x; i < S; i += stride) {
        float4 q0 = A4[i];
        float4 q1 = A4[i + S];
        float4 q2 = A4[i + 2 * S];
        float4 q3 = A4[i + 3 * S];
        float4 q4 = A4[i + 4 * S];
        int u  = (int)(i >> 10);            // 1024 float4 per row
        int v0 = ((int)i & 1023) << 2;
#define DO_COMP(comp, joff)                                                      \
        {                                                                        \
            float a0 = q0.comp, a1 = q1.comp, a2 = q2.comp,                      \
                  a3 = q3.comp, a4 = q4.comp;                                    \
            if (a0 != 0.f || a1 != 0.f || a2 != 0.f || a3 != 0.f || a4 != 0.f) { \
                float sA0 = fA0[0]*a0 + fA0[1]*a1 + fA0[2]*a2 + fA0[3]*a3 + fA0[4]*a4; \
                float sA1 = fA1[0]*a0 + fA1[1]*a1 + fA1[2]*a2 + fA1[3]*a3 + fA1[4]*a4; \
                float sB0 = fB0[0]*a0 + fB0[1]*a1 + fB0[2]*a2 + fB0[3]*a3 + fB0[4]*a4; \
                float sB1 = fB1[0]*a0 + fB1[1]*a1 + fB1[2]*a2 + fB1[3]*a3 + fB1[4]*a4; \
                float sC0 = fC0[0]*a0 + fC0[1]*a1 + fC0[2]*a2 + fC0[3]*a3 + fC0[4]*a4; \
                float sC1 = fC1[0]*a0 + fC1[1]*a1 + fC1[2]*a2 + fC1[3]*a3 + fC1[4]*a4; \
                int v = v0 + joff;                                               \
                int pos = atomicAdd(&cnt[v], 1);                                 \
                if (pos < CAP) {                                                 \
                    int slot = v * CAP + pos;                                    \
                    eu[slot] = u;                                                \
                    wA[slot] = float2{__expf(sA0), __expf(sA1)};                 \
                    wB[slot] = float2{__expf(sB0), __expf(sB1)};                 \
                    wC[slot] = float2{sC0, sC1};                                 \
                }                                                                \
            }                                                                    \
        }
        DO_COMP(x, 0)
        DO_COMP(y, 1)
        DO_COMP(z, 2)
        DO_COMP(w, 3)
#undef DO_COMP
    }
}

// One workgroup (256 threads) per column v; both channels.
// Phase 1: stage edges into LDS, reduce weight-sums + denominators.
// Phase 2: 8 edge-groups x 32 lanes, float4/bf16x4 row gathers, LDS tree reduce.
// STAGE 0: gather h (fp32, shared by channels), softmax-norm, denom = sum(w)
// STAGE 1: gather bf16 panel per channel, softmax-norm, denom from Dd_in
// STAGE 2: gather bf16 panel per channel, no norm, denom from Dd_in
template<int STAGE>
__global__ __launch_bounds__(256) void spmm_col(
    const int*    __restrict__ cnt,
    const int*    __restrict__ eu,
    const float2* __restrict__ ew,
    const float*  __restrict__ Xf,      // stage 0 only: h [NN][FINF]
    const ushort* __restrict__ Xb_in,   // stages 1/2: [NC][NN][FINF] bf16
    const float*  __restrict__ Dd_in,   // stages 1/2: [NC][NN]
    float*        __restrict__ Y,       // [NC][NN][YP] fp32
    ushort*       __restrict__ Xb_out,  // stages 0/1
    float*        __restrict__ Dd_out)  // stages 0/1
{
    int v = blockIdx.x;
    int n = cnt[v];
    if (n > CAP) n = CAP;

    __shared__ float4 s_e[CAP];          // {u bits, w0, w1, pad}
    __shared__ float  s_red[4];          // sum0, sum1, d0, d1
    __shared__ float4 s_acc[NC][8][32];  // 8 KB partial sums

    int tid = threadIdx.x;
    if (tid < 4) s_red[tid] = 0.f;
    __syncthreads();

    float l0 = 0.f, l1 = 0.f, ld0 = 0.f, ld1 = 0.f;
    for (int i = tid; i < n; i += 256) {
        int    u = eu[v * CAP + i];
        float2 w = ew[v * CAP + i];
        s_e[i] = float4{__int_as_float(u), w.x, w.y, 0.f};
        l0 += w.x;
        l1 += w.y;
        if (STAGE != 0) {
            ld0 += w.x * Dd_in[u];
            ld1 += w.y * Dd_in[NN + u];
        }
    }
    if (STAGE == 0) { ld0 = l0; ld1 = l1; }

#pragma unroll
    for (int m = 32; m >= 1; m >>= 1) {
        l0  += __shfl_xor(l0,  m);
        l1  += __shfl_xor(l1,  m);
        ld0 += __shfl_xor(ld0, m);
        ld1 += __shfl_xor(ld1, m);
    }
    if ((tid & 63) == 0) {
        atomicAdd(&s_red[0], l0);
        atomicAdd(&s_red[1], l1);
        atomicAdd(&s_red[2], ld0);
        atomicAdd(&s_red[3], ld1);
    }
    __syncthreads();

    int grp = tid >> 5, lane = tid & 31;
    float4 a0 = {0.f, 0.f, 0.f, 0.f};
    float4 a1 = {0.f, 0.f, 0.f, 0.f};

    if (STAGE == 0) {
        const float4* X4 = (const float4*)Xf;        // [NN][32]
        for (int i = grp; i < n; i += 8) {
            float4 e = s_e[i];
            float4 x = X4[(size_t)__float_as_int(e.x) * 32 + lane];
            a0.x += e.y * x.x; a0.y += e.y * x.y; a0.z += e.y * x.z; a0.w += e.y * x.w;
            a1.x += e.z * x.x; a1.y += e.z * x.y; a1.z += e.z * x.z; a1.w += e.z * x.w;
        }
    } else {
        const uint2* P0 = (const uint2*)Xb_in;       // [NN][32] uint2 per channel
        const uint2* P1 = P0 + (size_t)NN * 32;
        for (int i = grp; i < n; i += 8) {
            float4 e = s_e[i];
            int u = __float_as_int(e.x);
            uint2 b0 = P0[(size_t)u * 32 + lane];
            uint2 b1 = P1[(size_t)u * 32 + lane];
            a0.x += e.y * __uint_as_float(b0.x << 16);
            a0.y += e.y * __uint_as_float(b0.x & 0xffff0000u);
            a0.z += e.y * __uint_as_float(b0.y << 16);
            a0.w += e.y * __uint_as_float(b0.y & 0xffff0000u);
            a1.x += e.z * __uint_as_float(b1.x << 16);
            a1.y += e.z * __uint_as_float(b1.x & 0xffff0000u);
            a1.z += e.z * __uint_as_float(b1.y << 16);
            a1.w += e.z * __uint_as_float(b1.y & 0xffff0000u);
        }
    }

    s_acc[0][grp][lane] = a0;
    s_acc[1][grp][lane] = a1;
    __syncthreads();

    int c = tid >> 7, f = tid & 127;
    const float* base = (const float*)s_acc[c];      // [8][128] floats
    float s = 0.f;
#pragma unroll
    for (int g = 0; g < 8; ++g) s += base[g * 128 + f];

    float inv = 1.f;
    if (STAGE < 2 && n > 0) inv = 1.f / s_red[c];
    float val = s * inv;

    float* yrow = Y + ((size_t)c * NN + v) * YP;
    yrow[f] = val;
    if (STAGE < 2) {
        __hip_bfloat16 hb = __float2bfloat16(val);
        Xb_out[((size_t)c * NN + v) * FINF + f] = *(const ushort*)&hb;
    }
    if (f == 0) {
        float dvn = s_red[2 + c] * inv;
        yrow[FINF] = dvn;
        if (STAGE < 2) Dd_out[c * NN + v] = dvn;
    }
}

// out[c,l,v,o] = relu( (sum_f Y_l[c][v][f] gW[c,f,o]) * inv_d + gb[c,o] )
__global__ __launch_bounds__(64) void gcn_out(
    const float* __restrict__ YA,
    const float* __restrict__ Y1,
    const float* __restrict__ Y2,
    const float* __restrict__ gW,   // [NC, FINF, FOUTF]
    const float* __restrict__ gb,   // [NC, FOUTF]
    float* __restrict__ out)        // [NC, 3, NN, FOUTF]
{
    const int grids_per_cl = NN / VB;
    int b   = blockIdx.x;
    int grp = b / grids_per_cl;           // cl = c*3 + l
    int v0  = (b % grids_per_cl) * VB;
    int c = grp / 3, l = grp % 3;
    const float* Y = (l == 0) ? YA : (l == 1) ? Y1 : Y2;

    __shared__ float s_y[VB][FINF];
    __shared__ float s_inv[VB];
    int t = threadIdx.x;

    for (int k = t; k < VB * (FINF / 4); k += 64) {
        int r = k >> 5, c4 = k & 31;
        float4 q = *(const float4*)(Y + ((size_t)c * NN + v0 + r) * YP + c4 * 4);
        *(float4*)&s_y[r][c4 * 4] = q;
    }
    if (t < VB) {
        float d = Y[((size_t)c * NN + v0 + t) * YP + FINF];
        s_inv[t] = (d != 0.f) ? (1.f / d) : 1.f;
    }
    __syncthreads();

    float acc[VB];
#pragma unroll
    for (int r = 0; r < VB; ++r) acc[r] = 0.f;

    const float* w = gW + (size_t)c * FINF * FOUTF + t;
    for (int f4 = 0; f4 < FINF / 4; ++f4) {
        float w0 = w[(size_t)(f4 * 4 + 0) * FOUTF];
        float w1 = w[(size_t)(f4 * 4 + 1) * FOUTF];
        float w2 = w[(size_t)(f4 * 4 + 2) * FOUTF];
        float w3 = w[(size_t)(f4 * 4 + 3) * FOUTF];
#pragma unroll
        for (int r = 0; r < VB; ++r) {
            float4 y4 = *(const float4*)&s_y[r][f4 * 4];
            acc[r] += y4.x * w0 + y4.y * w1 + y4.z * w2 + y4.w * w3;
        }
    }

    float bias = gb[c * FOUTF + t];
#pragma unroll
    for (int r = 0; r < VB; ++r) {
        float val = acc[r] * s_inv[r] + bias;
        out[((size_t)grp * NN + v0 + r) * FOUTF + t] = fmaxf(val, 0.f);
    }
}

extern "C" void kernel_launch(void* const* d_in, const int* in_sizes, int n_in,
                              void* d_out, int out_size, void* d_ws, size_t ws_size,
                              hipStream_t stream)
{
    const float* A     = (const float*)d_in[0];
    const float* h     = (const float*)d_in[1];
    const float* W1_0  = (const float*)d_in[2];
    const float* W2_0  = (const float*)d_in[3];
    const float* W1_1  = (const float*)d_in[4];
    const float* gW    = (const float*)d_in[5];
    const float* gb    = (const float*)d_in[6];
    float* out = (float*)d_out;

    char* ws = (char*)d_ws;
    int*    cnt = (int*)(ws);
    int*    eu  = (int*)(ws + 16384);
    float2* wA  = (float2*)(ws + 6307840);
    float2* wB  = (float2*)(ws + 18890752);
    float2* wC  = (float2*)(ws + 31473664);
    float*  YA  = (float*)(ws + 44056576);
    float*  Y1  = (float*)(ws + 48381952);
    float*  Y2  = (float*)(ws + 52707328);
    float*  DdA = (float*)(ws + 57032704);
    float*  Dd1 = (float*)(ws + 57065472);
    ushort* XbA = (ushort*)(ws + 57098240);
    ushort* Xb1 = (ushort*)(ws + 59195392);

    zero_cnt<<<4, 256, 0, stream>>>((int4*)cnt);
    build_csc<<<2048, 256, 0, stream>>>(A, W1_0, W2_0, W1_1, cnt, eu, wA, wB, wC);

    // Stage A: Y_A = RA^T [h|1]            (softmax weights wA, gather fp32 h)
    spmm_col<0><<<NN, 256, 0, stream>>>(cnt, eu, wA, h, nullptr, nullptr, YA, XbA, DdA);
    // Stage B: Y_1 = RB^T Y_A = H0^T [h|1] (softmax weights wB, gather bf16 XbA)
    spmm_col<1><<<NN, 256, 0, stream>>>(cnt, eu, wB, nullptr, XbA, DdA, Y1, Xb1, Dd1);
    // Stage C: Y_2 = RB1^T Y_1 = H1^T [h|1] (raw weights wC, gather bf16 Xb1)
    spmm_col<2><<<NN, 256, 0, stream>>>(cnt, eu, wC, nullptr, Xb1, Dd1, Y2, nullptr, nullptr);

    gcn_out<<<6 * NN / VB, 64, 0, stream>>>(YA, Y1, Y2, gW, gb, out);
}